// Round 1
// baseline (1870.076 us; speedup 1.0000x reference)
//
#include <hip/hip_runtime.h>
#include <hip/hip_bf16.h>

#define M_DIM 8192
#define N_DIM 11008
#define K_DIM 4096
#define BM 128
#define BN 128
#define BK 64

typedef __attribute__((ext_vector_type(8))) short bf16x8;
typedef __attribute__((ext_vector_type(4))) float f32x4;

__device__ __forceinline__ short f2bf(float f) {
    __hip_bfloat16 h = __float2bfloat16(f);  // RNE
    short s;
    __builtin_memcpy(&s, &h, sizeof(s));
    return s;
}

__global__ __launch_bounds__(256, 2)
void wo_int8_gemm(const float* __restrict__ X, const int* __restrict__ W,
                  const float* __restrict__ SC, float* __restrict__ Out)
{
    __shared__ short As[BM * BK];  // bf16 bits, XOR-swizzled
    __shared__ short Bs[BN * BK];

    const int tid  = threadIdx.x;
    const int lane = tid & 63;
    const int wid  = tid >> 6;   // 0..3
    const int wr   = wid >> 1;   // wave row 0..1
    const int wc   = wid & 1;    // wave col 0..1

    const int brow = blockIdx.y * BM;
    const int bcol = blockIdx.x * BN;

    // staging: thread covers 8 contiguous k-elems of one row, 4 row-passes
    const int srow = tid >> 3;        // 0..31
    const int scol = (tid & 7) << 3;  // 0..56

    // fragment addressing
    const int arow   = wr * 64 + (lane & 15);
    const int brow_f = wc * 64 + (lane & 15);
    const int koff   = (lane >> 4) << 3;  // 0,8,16,24

    f32x4 acc[4][4] = {};

    for (int k0 = 0; k0 < K_DIM; k0 += BK) {
        __syncthreads();  // previous iteration's frag reads done

        // ---- stage A: x fp32 -> bf16 (RNE) ----
        #pragma unroll
        for (int p = 0; p < 4; ++p) {
            const int r = p * 32 + srow;
            const float4* xs = reinterpret_cast<const float4*>(
                X + (size_t)(brow + r) * K_DIM + (k0 + scol));
            float4 a0 = xs[0];
            float4 a1 = xs[1];
            bf16x8 v;
            v[0] = f2bf(a0.x); v[1] = f2bf(a0.y); v[2] = f2bf(a0.z); v[3] = f2bf(a0.w);
            v[4] = f2bf(a1.x); v[5] = f2bf(a1.y); v[6] = f2bf(a1.z); v[7] = f2bf(a1.w);
            const int idx = (r * BK + scol) ^ ((r & 7) << 3);  // swizzle (short units)
            *reinterpret_cast<bf16x8*>(&As[idx]) = v;
        }
        // ---- stage B: weight int8-in-int32 -> bf16 (exact) ----
        #pragma unroll
        for (int p = 0; p < 4; ++p) {
            const int r = p * 32 + srow;
            const int4* ws = reinterpret_cast<const int4*>(
                W + (size_t)(bcol + r) * K_DIM + (k0 + scol));
            int4 b0 = ws[0];
            int4 b1 = ws[1];
            bf16x8 v;
            v[0] = f2bf((float)b0.x); v[1] = f2bf((float)b0.y);
            v[2] = f2bf((float)b0.z); v[3] = f2bf((float)b0.w);
            v[4] = f2bf((float)b1.x); v[5] = f2bf((float)b1.y);
            v[6] = f2bf((float)b1.z); v[7] = f2bf((float)b1.w);
            const int idx = (r * BK + scol) ^ ((r & 7) << 3);
            *reinterpret_cast<bf16x8*>(&Bs[idx]) = v;
        }
        __syncthreads();

        // ---- compute: 2 k-steps of 16x16x32, 4x4 fragment grid per wave ----
        #pragma unroll
        for (int ks = 0; ks < 2; ++ks) {
            const int kb = ks * 32 + koff;
            bf16x8 af[4], bfr[4];
            #pragma unroll
            for (int m = 0; m < 4; ++m) {
                const int r = arow + m * 16;
                const int idx = (r * BK + kb) ^ ((r & 7) << 3);
                af[m] = *reinterpret_cast<const bf16x8*>(&As[idx]);
            }
            #pragma unroll
            for (int n = 0; n < 4; ++n) {
                const int r = brow_f + n * 16;
                const int idx = (r * BK + kb) ^ ((r & 7) << 3);
                bfr[n] = *reinterpret_cast<const bf16x8*>(&Bs[idx]);
            }
            #pragma unroll
            for (int m = 0; m < 4; ++m)
                #pragma unroll
                for (int n = 0; n < 4; ++n)
                    acc[m][n] = __builtin_amdgcn_mfma_f32_16x16x32_bf16(
                        af[m], bfr[n], acc[m][n], 0, 0, 0);
        }
    }

    // ---- epilogue: scale per out-channel, fp32 store ----
    // C/D layout (16x16x32 bf16): col = lane&15, row = (lane>>4)*4 + j
    const int orow0 = brow + wr * 64 + ((lane >> 4) << 2);
    const int ocol0 = bcol + wc * 64 + (lane & 15);
    #pragma unroll
    for (int n = 0; n < 4; ++n) {
        const float sc = SC[ocol0 + n * 16];
        #pragma unroll
        for (int m = 0; m < 4; ++m) {
            #pragma unroll
            for (int j = 0; j < 4; ++j) {
                Out[(size_t)(orow0 + m * 16 + j) * N_DIM + (ocol0 + n * 16)]
                    = acc[m][n][j] * sc;
            }
        }
    }
}

extern "C" void kernel_launch(void* const* d_in, const int* in_sizes, int n_in,
                              void* d_out, int out_size, void* d_ws, size_t ws_size,
                              hipStream_t stream) {
    const float* X  = (const float*)d_in[0];   // [8192, 4096] fp32
    const int*   W  = (const int*)d_in[1];     // [11008, 4096] int32 (int8 range)
    const float* SC = (const float*)d_in[2];   // [11008] fp32
    float* Out = (float*)d_out;                // [8192, 11008] fp32

    dim3 grid(N_DIM / BN, M_DIM / BM);  // (86, 64)
    wo_int8_gemm<<<grid, 256, 0, stream>>>(X, W, SC, Out);
}

// Round 2
// 981.508 us; speedup vs baseline: 1.9053x; 1.9053x over previous
//
#include <hip/hip_runtime.h>
#include <hip/hip_bf16.h>

#define M_DIM 8192
#define N_DIM 11008
#define K_DIM 4096
#define BM 128
#define BN 128
#define BK 64

typedef __attribute__((ext_vector_type(8))) short bf16x8;
typedef __attribute__((ext_vector_type(4))) float f32x4;

__device__ __forceinline__ short f2bf(float f) {
    __hip_bfloat16 h = __float2bfloat16(f);  // RNE
    short s;
    __builtin_memcpy(&s, &h, sizeof(s));
    return s;
}

__device__ __forceinline__ void gload_lds16(const void* g, void* l) {
    __builtin_amdgcn_global_load_lds(
        (const __attribute__((address_space(1))) unsigned int*)g,
        (__attribute__((address_space(3))) unsigned int*)l, 16, 0, 0);
}

// ---------------- pass 1: conversion kernels ----------------

__global__ __launch_bounds__(256)
void cvt_x_bf16(const float* __restrict__ X, short* __restrict__ Xb, int n8) {
    int i = blockIdx.x * blockDim.x + threadIdx.x;
    const int stride = gridDim.x * blockDim.x;
    for (; i < n8; i += stride) {
        const float4* p = reinterpret_cast<const float4*>(X + (size_t)i * 8);
        float4 a = p[0], b = p[1];
        bf16x8 v;
        v[0] = f2bf(a.x); v[1] = f2bf(a.y); v[2] = f2bf(a.z); v[3] = f2bf(a.w);
        v[4] = f2bf(b.x); v[5] = f2bf(b.y); v[6] = f2bf(b.z); v[7] = f2bf(b.w);
        *reinterpret_cast<bf16x8*>(Xb + (size_t)i * 8) = v;
    }
}

__global__ __launch_bounds__(256)
void cvt_w_bf16(const int* __restrict__ W, short* __restrict__ Wb, int n8) {
    int i = blockIdx.x * blockDim.x + threadIdx.x;
    const int stride = gridDim.x * blockDim.x;
    for (; i < n8; i += stride) {
        const int4* p = reinterpret_cast<const int4*>(W + (size_t)i * 8);
        int4 a = p[0], b = p[1];
        bf16x8 v;  // int8-range values are exact in bf16
        v[0] = f2bf((float)a.x); v[1] = f2bf((float)a.y);
        v[2] = f2bf((float)a.z); v[3] = f2bf((float)a.w);
        v[4] = f2bf((float)b.x); v[5] = f2bf((float)b.y);
        v[6] = f2bf((float)b.z); v[7] = f2bf((float)b.w);
        *reinterpret_cast<bf16x8*>(Wb + (size_t)i * 8) = v;
    }
}

// ---------------- pass 2: bf16 GEMM, m97 structure ----------------
// 128x128 tile, BK=64, 4 waves (2x2, 64x64 each), global_load_lds width 16,
// linear LDS (required by wave-uniform-base + lane*16 write pattern).

__global__ __launch_bounds__(256, 2)
void gemm_bf16(const short* __restrict__ Xb, const short* __restrict__ Wb,
               const float* __restrict__ SC, float* __restrict__ Out)
{
    __shared__ short As[BM * BK];  // 16 KB
    __shared__ short Bs[BN * BK];  // 16 KB

    // XCD-aware bijective swizzle: nwg = 5504 = 8 * 688
    const int NWG_N = N_DIM / BN;  // 86
    const int wg = blockIdx.x;
    const int swz = (wg & 7) * 688 + (wg >> 3);
    const int by = swz / NWG_N;
    const int bx = swz - by * NWG_N;

    const int tid  = threadIdx.x;
    const int lane = tid & 63;
    const int w    = tid >> 6;
    const int wr   = w >> 1;
    const int wc   = w & 1;

    const int brow = by * BM;
    const int bcol = bx * BN;

    // staging: thread covers 8 contiguous k of one row; 4 issues cover 128 rows
    const short* ga = Xb + (size_t)(brow + (tid >> 3)) * K_DIM + ((tid & 7) << 3);
    const short* gb = Wb + (size_t)(bcol + (tid >> 3)) * K_DIM + ((tid & 7) << 3);
    short* As_w = &As[w * 512];  // wave-uniform LDS base (shorts): w*1024 bytes
    short* Bs_w = &Bs[w * 512];

    // fragment addressing
    const int arow   = wr * 64 + (lane & 15);
    const int brow_f = wc * 64 + (lane & 15);
    const int koff   = (lane >> 4) << 3;  // 0,8,16,24

    f32x4 acc[4][4] = {};

    for (int k0 = 0; k0 < K_DIM; k0 += BK) {
        __syncthreads();  // previous iteration's LDS reads complete
        #pragma unroll
        for (int p = 0; p < 4; ++p) {
            gload_lds16(ga + (size_t)p * 32 * K_DIM + k0, As_w + p * 2048);
            gload_lds16(gb + (size_t)p * 32 * K_DIM + k0, Bs_w + p * 2048);
        }
        __syncthreads();  // compiler drains vmcnt before barrier

        #pragma unroll
        for (int ks = 0; ks < 2; ++ks) {
            const int kb = ks * 32 + koff;
            bf16x8 af[4], bfr[4];
            #pragma unroll
            for (int m = 0; m < 4; ++m)
                af[m] = *reinterpret_cast<const bf16x8*>(&As[(arow + m * 16) * BK + kb]);
            #pragma unroll
            for (int n = 0; n < 4; ++n)
                bfr[n] = *reinterpret_cast<const bf16x8*>(&Bs[(brow_f + n * 16) * BK + kb]);
            #pragma unroll
            for (int m = 0; m < 4; ++m)
                #pragma unroll
                for (int n = 0; n < 4; ++n)
                    acc[m][n] = __builtin_amdgcn_mfma_f32_16x16x32_bf16(
                        af[m], bfr[n], acc[m][n], 0, 0, 0);
        }
    }

    // epilogue: per-out-channel scale, fp32 store
    // C/D layout (16x16x32 bf16): col = lane&15, row = (lane>>4)*4 + j
    const int orow0 = brow + wr * 64 + ((lane >> 4) << 2);
    const int ocol0 = bcol + wc * 64 + (lane & 15);
    #pragma unroll
    for (int n = 0; n < 4; ++n) {
        const float sc = SC[ocol0 + n * 16];
        #pragma unroll
        for (int m = 0; m < 4; ++m)
            #pragma unroll
            for (int j = 0; j < 4; ++j)
                Out[(size_t)(orow0 + m * 16 + j) * N_DIM + (ocol0 + n * 16)]
                    = acc[m][n][j] * sc;
    }
}

// ---------------- fallback: round-1 fused kernel (if ws too small) ----------------

__global__ __launch_bounds__(256, 2)
void wo_int8_gemm_fused(const float* __restrict__ X, const int* __restrict__ W,
                        const float* __restrict__ SC, float* __restrict__ Out)
{
    __shared__ short As[BM * BK];
    __shared__ short Bs[BN * BK];

    const int tid  = threadIdx.x;
    const int lane = tid & 63;
    const int wid  = tid >> 6;
    const int wr   = wid >> 1;
    const int wc   = wid & 1;
    const int brow = blockIdx.y * BM;
    const int bcol = blockIdx.x * BN;
    const int srow = tid >> 3;
    const int scol = (tid & 7) << 3;
    const int arow   = wr * 64 + (lane & 15);
    const int brow_f = wc * 64 + (lane & 15);
    const int koff   = (lane >> 4) << 3;

    f32x4 acc[4][4] = {};

    for (int k0 = 0; k0 < K_DIM; k0 += BK) {
        __syncthreads();
        #pragma unroll
        for (int p = 0; p < 4; ++p) {
            const int r = p * 32 + srow;
            const float4* xs = reinterpret_cast<const float4*>(
                X + (size_t)(brow + r) * K_DIM + (k0 + scol));
            float4 a0 = xs[0], a1 = xs[1];
            bf16x8 v;
            v[0] = f2bf(a0.x); v[1] = f2bf(a0.y); v[2] = f2bf(a0.z); v[3] = f2bf(a0.w);
            v[4] = f2bf(a1.x); v[5] = f2bf(a1.y); v[6] = f2bf(a1.z); v[7] = f2bf(a1.w);
            const int idx = (r * BK + scol) ^ ((r & 7) << 3);
            *reinterpret_cast<bf16x8*>(&As[idx]) = v;
        }
        #pragma unroll
        for (int p = 0; p < 4; ++p) {
            const int r = p * 32 + srow;
            const int4* ws = reinterpret_cast<const int4*>(
                W + (size_t)(bcol + r) * K_DIM + (k0 + scol));
            int4 b0 = ws[0], b1 = ws[1];
            bf16x8 v;
            v[0] = f2bf((float)b0.x); v[1] = f2bf((float)b0.y);
            v[2] = f2bf((float)b0.z); v[3] = f2bf((float)b0.w);
            v[4] = f2bf((float)b1.x); v[5] = f2bf((float)b1.y);
            v[6] = f2bf((float)b1.z); v[7] = f2bf((float)b1.w);
            const int idx = (r * BK + scol) ^ ((r & 7) << 3);
            *reinterpret_cast<bf16x8*>(&Bs[idx]) = v;
        }
        __syncthreads();
        #pragma unroll
        for (int ks = 0; ks < 2; ++ks) {
            const int kb = ks * 32 + koff;
            bf16x8 af[4], bfr[4];
            #pragma unroll
            for (int m = 0; m < 4; ++m) {
                const int r = arow + m * 16;
                af[m] = *reinterpret_cast<const bf16x8*>(&As[(r * BK + kb) ^ ((r & 7) << 3)]);
            }
            #pragma unroll
            for (int n = 0; n < 4; ++n) {
                const int r = brow_f + n * 16;
                bfr[n] = *reinterpret_cast<const bf16x8*>(&Bs[(r * BK + kb) ^ ((r & 7) << 3)]);
            }
            #pragma unroll
            for (int m = 0; m < 4; ++m)
                #pragma unroll
                for (int n = 0; n < 4; ++n)
                    acc[m][n] = __builtin_amdgcn_mfma_f32_16x16x32_bf16(
                        af[m], bfr[n], acc[m][n], 0, 0, 0);
        }
    }

    const int orow0 = brow + wr * 64 + ((lane >> 4) << 2);
    const int ocol0 = bcol + wc * 64 + (lane & 15);
    #pragma unroll
    for (int n = 0; n < 4; ++n) {
        const float sc = SC[ocol0 + n * 16];
        #pragma unroll
        for (int m = 0; m < 4; ++m)
            #pragma unroll
            for (int j = 0; j < 4; ++j)
                Out[(size_t)(orow0 + m * 16 + j) * N_DIM + (ocol0 + n * 16)]
                    = acc[m][n][j] * sc;
    }
}

extern "C" void kernel_launch(void* const* d_in, const int* in_sizes, int n_in,
                              void* d_out, int out_size, void* d_ws, size_t ws_size,
                              hipStream_t stream) {
    const float* X  = (const float*)d_in[0];   // [8192, 4096] fp32
    const int*   W  = (const int*)d_in[1];     // [11008, 4096] int32 (int8 range)
    const float* SC = (const float*)d_in[2];   // [11008] fp32
    float* Out = (float*)d_out;                // [8192, 11008] fp32

    const size_t xb_bytes = (size_t)M_DIM * K_DIM * 2;          // 64 MiB
    const size_t wb_bytes = (size_t)N_DIM * K_DIM * 2;          // 86 MiB
    if (ws_size >= xb_bytes + wb_bytes) {
        short* Xb = (short*)d_ws;
        short* Wb = (short*)((char*)d_ws + xb_bytes);
        cvt_x_bf16<<<2048, 256, 0, stream>>>(X, Xb, (int)((size_t)M_DIM * K_DIM / 8));
        cvt_w_bf16<<<2048, 256, 0, stream>>>(W, Wb, (int)((size_t)N_DIM * K_DIM / 8));
        gemm_bf16<<<(M_DIM / BM) * (N_DIM / BN), 256, 0, stream>>>(Xb, Wb, SC, Out);
    } else {
        dim3 grid(N_DIM / BN, M_DIM / BM);
        wo_int8_gemm_fused<<<grid, 256, 0, stream>>>(X, W, SC, Out);
    }
}

// Round 4
// 732.995 us; speedup vs baseline: 2.5513x; 1.3390x over previous
//
#include <hip/hip_runtime.h>
#include <hip/hip_bf16.h>

#define M_DIM 8192
#define N_DIM 11008
#define K_DIM 4096

typedef __attribute__((ext_vector_type(8))) short bf16x8;
typedef __attribute__((ext_vector_type(4))) float f32x4;

__device__ __forceinline__ short f2bf(float f) {
    __hip_bfloat16 h = __float2bfloat16(f);  // RNE
    short s;
    __builtin_memcpy(&s, &h, sizeof(s));
    return s;
}

__device__ __forceinline__ void gload_lds16(const void* g, void* l) {
    __builtin_amdgcn_global_load_lds(
        (const __attribute__((address_space(1))) unsigned int*)g,
        (__attribute__((address_space(3))) unsigned int*)l, 16, 0, 0);
}

// ---------------- pass 1: conversion kernels ----------------

__global__ __launch_bounds__(256)
void cvt_x_bf16(const float* __restrict__ X, short* __restrict__ Xb, int n8) {
    int i = blockIdx.x * blockDim.x + threadIdx.x;
    const int stride = gridDim.x * blockDim.x;
    for (; i < n8; i += stride) {
        const float4* p = reinterpret_cast<const float4*>(X + (size_t)i * 8);
        float4 a = p[0], b = p[1];
        bf16x8 v;
        v[0] = f2bf(a.x); v[1] = f2bf(a.y); v[2] = f2bf(a.z); v[3] = f2bf(a.w);
        v[4] = f2bf(b.x); v[5] = f2bf(b.y); v[6] = f2bf(b.z); v[7] = f2bf(b.w);
        *reinterpret_cast<bf16x8*>(Xb + (size_t)i * 8) = v;
    }
}

__global__ __launch_bounds__(256)
void cvt_w_bf16(const int* __restrict__ W, short* __restrict__ Wb, int n8) {
    int i = blockIdx.x * blockDim.x + threadIdx.x;
    const int stride = gridDim.x * blockDim.x;
    for (; i < n8; i += stride) {
        const int4* p = reinterpret_cast<const int4*>(W + (size_t)i * 8);
        int4 a = p[0], b = p[1];
        bf16x8 v;  // int8-range values exact in bf16
        v[0] = f2bf((float)a.x); v[1] = f2bf((float)a.y);
        v[2] = f2bf((float)a.z); v[3] = f2bf((float)a.w);
        v[4] = f2bf((float)b.x); v[5] = f2bf((float)b.y);
        v[6] = f2bf((float)b.z); v[7] = f2bf((float)b.w);
        *reinterpret_cast<bf16x8*>(Wb + (size_t)i * 8) = v;
    }
}

// ---------------- pass 2: 256x256 8-phase bf16 GEMM ----------------
// 8 waves (2Mx4N), BK=64, 2 LDS tile-buffers (128 KiB), chunk-XOR swizzle
// via pre-swizzled global_load_lds source, counted vmcnt (never 0 in loop).

// stage half-tile H (128 rows) of tile T into buffer B: 2 loads/thread
#define STA(T, B, H) do { \
    const short* s_ = gA + (size_t)((H) * 128) * K_DIM + (T) * 64; \
    char* d_ = As + (B) * 32768 + (H) * 16384 + aw; \
    gload_lds16(s_, d_); \
    gload_lds16(s_ + (size_t)64 * K_DIM, d_ + 8192); \
} while (0)

#define STB(T, B, H) do { \
    const short* s_ = gB + (size_t)((H) * 128) * K_DIM + (T) * 64; \
    char* d_ = Bs + (B) * 32768 + (H) * 16384 + aw; \
    gload_lds16(s_, d_); \
    gload_lds16(s_ + (size_t)64 * K_DIM, d_ + 8192); \
} while (0)

// MODE: 0 = steady (issue A t+1, B t+2, vmcnt(4))
//       1 = t==62 (issue A t+1 only, vmcnt(0))
//       2 = t==63 (no issues, no vmcnt)
#define TILE_BODY(T, B, MODE) do { \
    bf16x8 a0[4][2], a1[4][2], b0[2][2], b1[2][2]; \
    /* ---- P0: read A m0-3 + B n0-1; issue A(t+1,h0) ---- */ \
    _Pragma("unroll") for (int m = 0; m < 4; ++m) { \
        a0[m][0] = *(const bf16x8*)(As + (B) * 32768 + fa + m * 2048 + cs0); \
        a0[m][1] = *(const bf16x8*)(As + (B) * 32768 + fa + m * 2048 + cs1); } \
    _Pragma("unroll") for (int n = 0; n < 2; ++n) { \
        b0[n][0] = *(const bf16x8*)(Bs + (B) * 32768 + fb + n * 2048 + cs0); \
        b0[n][1] = *(const bf16x8*)(Bs + (B) * 32768 + fb + n * 2048 + cs1); } \
    if ((MODE) < 2) STA((T) + 1, 1 - (B), 0); \
    __builtin_amdgcn_s_barrier(); \
    asm volatile("s_waitcnt lgkmcnt(0)" ::: "memory"); \
    __builtin_amdgcn_s_setprio(1); \
    _Pragma("unroll") for (int m = 0; m < 4; ++m) \
    _Pragma("unroll") for (int n = 0; n < 2; ++n) { \
        acc[m][n] = __builtin_amdgcn_mfma_f32_16x16x32_bf16(a0[m][0], b0[n][0], acc[m][n], 0, 0, 0); \
        acc[m][n] = __builtin_amdgcn_mfma_f32_16x16x32_bf16(a0[m][1], b0[n][1], acc[m][n], 0, 0, 0); } \
    __builtin_amdgcn_s_setprio(0); \
    __builtin_amdgcn_s_barrier(); \
    /* ---- P1: read B n2-3; issue A(t+1,h1) ---- */ \
    _Pragma("unroll") for (int n = 0; n < 2; ++n) { \
        b1[n][0] = *(const bf16x8*)(Bs + (B) * 32768 + fb + (n + 2) * 2048 + cs0); \
        b1[n][1] = *(const bf16x8*)(Bs + (B) * 32768 + fb + (n + 2) * 2048 + cs1); } \
    if ((MODE) < 2) STA((T) + 1, 1 - (B), 1); \
    __builtin_amdgcn_s_barrier(); \
    asm volatile("s_waitcnt lgkmcnt(0)" ::: "memory"); \
    __builtin_amdgcn_s_setprio(1); \
    _Pragma("unroll") for (int m = 0; m < 4; ++m) \
    _Pragma("unroll") for (int n = 0; n < 2; ++n) { \
        acc[m][n + 2] = __builtin_amdgcn_mfma_f32_16x16x32_bf16(a0[m][0], b1[n][0], acc[m][n + 2], 0, 0, 0); \
        acc[m][n + 2] = __builtin_amdgcn_mfma_f32_16x16x32_bf16(a0[m][1], b1[n][1], acc[m][n + 2], 0, 0, 0); } \
    __builtin_amdgcn_s_setprio(0); \
    __builtin_amdgcn_s_barrier(); \
    /* ---- P2: read A m4-7; issue B(t+2,h0) (t's B dead after P1, certified) ---- */ \
    _Pragma("unroll") for (int m = 0; m < 4; ++m) { \
        a1[m][0] = *(const bf16x8*)(As + (B) * 32768 + fa + (m + 4) * 2048 + cs0); \
        a1[m][1] = *(const bf16x8*)(As + (B) * 32768 + fa + (m + 4) * 2048 + cs1); } \
    if ((MODE) == 0) STB((T) + 2, (B), 0); \
    __builtin_amdgcn_s_barrier(); \
    asm volatile("s_waitcnt lgkmcnt(0)" ::: "memory"); \
    __builtin_amdgcn_s_setprio(1); \
    _Pragma("unroll") for (int m = 0; m < 4; ++m) \
    _Pragma("unroll") for (int n = 0; n < 2; ++n) { \
        acc[m + 4][n] = __builtin_amdgcn_mfma_f32_16x16x32_bf16(a1[m][0], b0[n][0], acc[m + 4][n], 0, 0, 0); \
        acc[m + 4][n] = __builtin_amdgcn_mfma_f32_16x16x32_bf16(a1[m][1], b0[n][1], acc[m + 4][n], 0, 0, 0); } \
    __builtin_amdgcn_s_setprio(0); \
    __builtin_amdgcn_s_barrier(); \
    /* ---- P3: no reads; issue B(t+2,h1); vmcnt BEFORE barrier2 certifies tile t+1 ---- */ \
    if ((MODE) == 0) STB((T) + 2, (B), 1); \
    __builtin_amdgcn_s_setprio(1); \
    _Pragma("unroll") for (int m = 0; m < 4; ++m) \
    _Pragma("unroll") for (int n = 0; n < 2; ++n) { \
        acc[m + 4][n + 2] = __builtin_amdgcn_mfma_f32_16x16x32_bf16(a1[m][0], b1[n][0], acc[m + 4][n + 2], 0, 0, 0); \
        acc[m + 4][n + 2] = __builtin_amdgcn_mfma_f32_16x16x32_bf16(a1[m][1], b1[n][1], acc[m + 4][n + 2], 0, 0, 0); } \
    __builtin_amdgcn_s_setprio(0); \
    if ((MODE) == 0) asm volatile("s_waitcnt vmcnt(4)" ::: "memory"); \
    if ((MODE) == 1) asm volatile("s_waitcnt vmcnt(0)" ::: "memory"); \
    __builtin_amdgcn_s_barrier(); \
} while (0)

__global__ __launch_bounds__(512, 2)
void gemm_bf16_8ph(const short* __restrict__ Xb, const short* __restrict__ Wb,
                   const float* __restrict__ SC, float* __restrict__ Out)
{
    __shared__ __attribute__((aligned(16))) char smem[131072];
    char* const As = smem;           // [2][256 rows][128 B], chunk-swizzled
    char* const Bs = smem + 65536;

    const int tid  = threadIdx.x;
    const int lane = tid & 63;
    const int w    = tid >> 6;   // 0..7
    const int wr   = w >> 2;     // 0..1
    const int wc   = w & 3;      // 0..3

    // XCD-aware bijective swizzle: nwg = 1376 = 8 * 172
    const int wg  = blockIdx.x;
    const int swz = (wg & 7) * 172 + (wg >> 3);
    const int by  = swz / 43;
    const int bx  = swz - by * 43;
    const int brow = by * 256;
    const int bcol = bx * 256;

    // staging: lane covers row (w*8 + lane/8), swizzled chunk (lane&7)^(lane>>3)
    const int lr = lane >> 3;
    const int lc = (lane & 7) ^ lr;
    const short* gA = Xb + (size_t)(brow + w * 8 + lr) * K_DIM + (lc << 3);
    const short* gB = Wb + (size_t)(bcol + w * 8 + lr) * K_DIM + (lc << 3);
    const int aw = w * 1024;  // wave rows offset in LDS dest (w*8 rows * 128B)

    // fragment read bases (byte offsets); chunk-XOR matches staging swizzle
    const int fa  = (wr * 128 + (lane & 15)) * 128;
    const int fb  = (wc * 64  + (lane & 15)) * 128;
    const int cs0 = (((lane >> 4) + 0) ^ (lane & 7)) * 16;
    const int cs1 = (((lane >> 4) + 4) ^ (lane & 7)) * 16;

    f32x4 acc[8][4] = {};

    // prologue: tile0 {B0,B1,A0,A1}, tile1 {B0,B1}; certify tile0, 1 half-pair in flight
    STB(0, 0, 0); STB(0, 0, 1); STA(0, 0, 0); STA(0, 0, 1);
    STB(1, 1, 0); STB(1, 1, 1);
    asm volatile("s_waitcnt vmcnt(4)" ::: "memory");
    __builtin_amdgcn_s_barrier();

    for (int t = 0; t < 62; t += 2) {
        TILE_BODY(t, 0, 0);
        TILE_BODY(t + 1, 1, 0);
    }
    TILE_BODY(62, 0, 1);
    TILE_BODY(63, 1, 2);

    // epilogue: per-out-channel scale, fp32 store
    // C/D layout: col = lane&15, row = (lane>>4)*4 + j
    const int orow0 = brow + wr * 128 + ((lane >> 4) << 2);
    const int ocol0 = bcol + wc * 64 + (lane & 15);
    #pragma unroll
    for (int n = 0; n < 4; ++n) {
        const float sc = SC[ocol0 + n * 16];
        #pragma unroll
        for (int m = 0; m < 8; ++m)
            #pragma unroll
            for (int j = 0; j < 4; ++j)
                Out[(size_t)(orow0 + m * 16 + j) * N_DIM + (ocol0 + n * 16)]
                    = acc[m][n][j] * sc;
    }
}

// ---------------- fallback: fused single-pass (if ws too small) ----------------

__global__ __launch_bounds__(256, 2)
void wo_int8_gemm_fused(const float* __restrict__ X, const int* __restrict__ W,
                        const float* __restrict__ SC, float* __restrict__ Out)
{
    __shared__ short Asf[128 * 64];
    __shared__ short Bsf[128 * 64];

    const int tid  = threadIdx.x;
    const int lane = tid & 63;
    const int wid  = tid >> 6;
    const int wrf  = wid >> 1;
    const int wcf  = wid & 1;
    const int brow = blockIdx.y * 128;
    const int bcol = blockIdx.x * 128;
    const int srow = tid >> 3;
    const int scol = (tid & 7) << 3;
    const int arow   = wrf * 64 + (lane & 15);
    const int brow_f = wcf * 64 + (lane & 15);
    const int koff   = (lane >> 4) << 3;

    f32x4 acc[4][4] = {};

    for (int k0 = 0; k0 < K_DIM; k0 += 64) {
        __syncthreads();
        #pragma unroll
        for (int p = 0; p < 4; ++p) {
            const int r = p * 32 + srow;
            const float4* xs = reinterpret_cast<const float4*>(
                X + (size_t)(brow + r) * K_DIM + (k0 + scol));
            float4 a0 = xs[0], a1 = xs[1];
            bf16x8 v;
            v[0] = f2bf(a0.x); v[1] = f2bf(a0.y); v[2] = f2bf(a0.z); v[3] = f2bf(a0.w);
            v[4] = f2bf(a1.x); v[5] = f2bf(a1.y); v[6] = f2bf(a1.z); v[7] = f2bf(a1.w);
            *reinterpret_cast<bf16x8*>(&Asf[(r * 64 + scol) ^ ((r & 7) << 3)]) = v;
        }
        #pragma unroll
        for (int p = 0; p < 4; ++p) {
            const int r = p * 32 + srow;
            const int4* ws = reinterpret_cast<const int4*>(
                W + (size_t)(bcol + r) * K_DIM + (k0 + scol));
            int4 b0 = ws[0], b1 = ws[1];
            bf16x8 v;
            v[0] = f2bf((float)b0.x); v[1] = f2bf((float)b0.y);
            v[2] = f2bf((float)b0.z); v[3] = f2bf((float)b0.w);
            v[4] = f2bf((float)b1.x); v[5] = f2bf((float)b1.y);
            v[6] = f2bf((float)b1.z); v[7] = f2bf((float)b1.w);
            *reinterpret_cast<bf16x8*>(&Bsf[(r * 64 + scol) ^ ((r & 7) << 3)]) = v;
        }
        __syncthreads();
        #pragma unroll
        for (int ks = 0; ks < 2; ++ks) {
            const int kb = ks * 32 + koff;
            bf16x8 af[4], bfr[4];
            #pragma unroll
            for (int m = 0; m < 4; ++m) {
                const int r = arow + m * 16;
                af[m] = *reinterpret_cast<const bf16x8*>(&Asf[(r * 64 + kb) ^ ((r & 7) << 3)]);
            }
            #pragma unroll
            for (int n = 0; n < 4; ++n) {
                const int r = brow_f + n * 16;
                bfr[n] = *reinterpret_cast<const bf16x8*>(&Bsf[(r * 64 + kb) ^ ((r & 7) << 3)]);
            }
            #pragma unroll
            for (int m = 0; m < 4; ++m)
                #pragma unroll
                for (int n = 0; n < 4; ++n)
                    acc[m][n] = __builtin_amdgcn_mfma_f32_16x16x32_bf16(
                        af[m], bfr[n], acc[m][n], 0, 0, 0);
        }
    }

    const int orow0 = brow + wrf * 64 + ((lane >> 4) << 2);
    const int ocol0 = bcol + wcf * 64 + (lane & 15);
    #pragma unroll
    for (int n = 0; n < 4; ++n) {
        const float sc = SC[ocol0 + n * 16];
        #pragma unroll
        for (int m = 0; m < 4; ++m)
            #pragma unroll
            for (int j = 0; j < 4; ++j)
                Out[(size_t)(orow0 + m * 16 + j) * N_DIM + (ocol0 + n * 16)]
                    = acc[m][n][j] * sc;
    }
}

extern "C" void kernel_launch(void* const* d_in, const int* in_sizes, int n_in,
                              void* d_out, int out_size, void* d_ws, size_t ws_size,
                              hipStream_t stream) {
    const float* X  = (const float*)d_in[0];   // [8192, 4096] fp32
    const int*   W  = (const int*)d_in[1];     // [11008, 4096] int32 (int8 range)
    const float* SC = (const float*)d_in[2];   // [11008] fp32
    float* Out = (float*)d_out;                // [8192, 11008] fp32

    const size_t xb_bytes = (size_t)M_DIM * K_DIM * 2;
    const size_t wb_bytes = (size_t)N_DIM * K_DIM * 2;
    if (ws_size >= xb_bytes + wb_bytes) {
        short* Xb = (short*)d_ws;
        short* Wb = (short*)((char*)d_ws + xb_bytes);
        cvt_x_bf16<<<2048, 256, 0, stream>>>(X, Xb, (int)((size_t)M_DIM * K_DIM / 8));
        cvt_w_bf16<<<2048, 256, 0, stream>>>(W, Wb, (int)((size_t)N_DIM * K_DIM / 8));
        gemm_bf16_8ph<<<(M_DIM / 256) * (N_DIM / 256), 512, 0, stream>>>(Xb, Wb, SC, Out);
    } else {
        dim3 grid(N_DIM / 128, M_DIM / 128);
        wo_int8_gemm_fused<<<grid, 256, 0, stream>>>(X, W, SC, Out);
    }
}